// Round 11
// baseline (1339.483 us; speedup 1.0000x reference)
//
#include <hip/hip_runtime.h>
#include <hip/hip_bf16.h>

typedef __attribute__((ext_vector_type(8))) short short8;
typedef __attribute__((ext_vector_type(4))) float f32x4;
typedef unsigned long long u64;

// z: [64, 256, 32, 32] f32 ; codebook: [512, 256] f32
// d_out f32: [z_q_st (16777216) | indices (65536) | loss (1)]
#define C_DIM   256
#define K_CODES 512
#define N_POS   65536
#define OUT0_ELEMS 16777216
#define OUT1_ELEMS 65536
#define EPS 0.06f   // candidate margin; approx error bound ~0.021 worst-case

// ---------------------------------------------------------------------------
// codebook -> bf16 hi/lo rows (same [code][c] layout; B-operand reads directly)
// ---------------------------------------------------------------------------
__global__ __launch_bounds__(256) void vq_convcb_kernel(const float* __restrict__ cb,
    __hip_bfloat16* __restrict__ Ch, __hip_bfloat16* __restrict__ Cl)
{
    const int i = blockIdx.x * 256 + threadIdx.x;   // 0..131071
    float v = cb[i];
    __hip_bfloat16 h = __float2bfloat16(v);
    __hip_bfloat16 l = __float2bfloat16(v - __bfloat162float(h));
    Ch[i] = h; Cl[i] = l;
}

// ---------------------------------------------------------------------------
// cc[k] = sum_c cb[k][c]^2, numpy pairwise order (proven numerics)
// ---------------------------------------------------------------------------
__global__ __launch_bounds__(256) void vq_cc_kernel(const float* __restrict__ cb,
                                                    float* __restrict__ cc)
{
    const int k = blockIdx.x * 256 + threadIdx.x;   // 2 blocks -> 0..511
    const float* row = cb + (size_t)k * C_DIM;
    float s1[8], s2[8];
    #pragma unroll
    for (int j = 0; j < 8; ++j) { s1[j] = 0.f; s2[j] = 0.f; }
    for (int c8 = 0; c8 < 16; ++c8)
        #pragma unroll
        for (int j = 0; j < 8; ++j) {
            float v = row[c8 * 8 + j];
            s1[j] = __fadd_rn(s1[j], __fmul_rn(v, v));
        }
    for (int c8 = 16; c8 < 32; ++c8)
        #pragma unroll
        for (int j = 0; j < 8; ++j) {
            float v = row[c8 * 8 + j];
            s2[j] = __fadd_rn(s2[j], __fmul_rn(v, v));
        }
    float b1 = __fadd_rn(__fadd_rn(__fadd_rn(s1[0], s1[1]), __fadd_rn(s1[2], s1[3])),
                         __fadd_rn(__fadd_rn(s1[4], s1[5]), __fadd_rn(s1[6], s1[7])));
    float b2 = __fadd_rn(__fadd_rn(__fadd_rn(s2[0], s2[1]), __fadd_rn(s2[2], s2[3])),
                         __fadd_rn(__fadd_rn(s2[4], s2[5]), __fadd_rn(s2[6], s2[7])));
    cc[k] = __fadd_rn(b1, b2);
}

// ---------------------------------------------------------------------------
// z -> Zh bf16 in [pos][c] layout (A-operand layout). Block: 32 pos x 256 c.
// ---------------------------------------------------------------------------
__global__ __launch_bounds__(256) void vq_splitz_kernel(const float* __restrict__ z,
    __hip_bfloat16* __restrict__ Zh)
{
    const int tid = threadIdx.x;
    const int p   = blockIdx.x * 32 + (tid >> 3);
    const int c8  = tid & 7;
    const float* zb = z + ((size_t)(p >> 10) << 18) + (p & 1023);
    __hip_bfloat16* out = Zh + (size_t)p * C_DIM;
    #pragma unroll
    for (int q = 0; q < 4; ++q) {
        const int c0 = q * 64 + c8 * 8;
        short8 pk;
        #pragma unroll
        for (int j = 0; j < 8; ++j) {
            float v = zb[(size_t)(c0 + j) << 10];
            __hip_bfloat16 h = __float2bfloat16(v);
            pk[j] = *reinterpret_cast<short*>(&h);
        }
        *reinterpret_cast<short8*>(out + c0) = pk;   // 16B contiguous per thread
    }
}

// ---------------------------------------------------------------------------
// MFMA screen: grid 2048 = pos-tile(1024, 64 pos) x cg(2, 256 codes).
// Wave w: 64 pos x 64 codes (4 m-frag x 4 n-frag), K=256 in 8 steps.
// s = cc - 2*(Zh.Ch + Zh.Cl); per-16-code-subgroup min -> bd[32][N_POS].
// A: lane l&15 = pos-row, 8 contiguous c at (kk*32 + (l>>4)*8). B: lane
// l&15 = code-row, same c-slice (native [code][c] rows = B^T-input pattern).
// D: col = l&15 (code), row = (l>>4)*4 + r (pos)  [m89-verified layout].
// ---------------------------------------------------------------------------
__global__ __launch_bounds__(256) void vq_mfma_kernel(
    const __hip_bfloat16* __restrict__ Zh, const __hip_bfloat16* __restrict__ Ch,
    const __hip_bfloat16* __restrict__ Cl, const float* __restrict__ ccv,
    float* __restrict__ bd)
{
    const int blk  = blockIdx.x;
    const int cg   = blk & 1;
    const int pt   = blk >> 1;
    const int tid  = threadIdx.x;
    const int lane = tid & 63;
    const int w    = tid >> 6;
    const int r16  = lane & 15;
    const int kg   = lane >> 4;
    const int code0 = cg * 256 + w * 64;

    f32x4 acc[4][4];
    #pragma unroll
    for (int mf = 0; mf < 4; ++mf)
        #pragma unroll
        for (int nf = 0; nf < 4; ++nf) acc[mf][nf] = (f32x4){0.f, 0.f, 0.f, 0.f};

    for (int kk = 0; kk < 8; ++kk) {
        const int cc0 = kk * 32 + kg * 8;
        short8 a[4];
        #pragma unroll
        for (int mf = 0; mf < 4; ++mf) {
            const int pos = (pt << 6) + (mf << 4) + r16;
            a[mf] = *reinterpret_cast<const short8*>(Zh + (size_t)pos * C_DIM + cc0);
        }
        #pragma unroll
        for (int nf = 0; nf < 4; ++nf) {
            const int code = code0 + nf * 16 + r16;
            short8 bh = *reinterpret_cast<const short8*>(Ch + (size_t)code * C_DIM + cc0);
            short8 bl = *reinterpret_cast<const short8*>(Cl + (size_t)code * C_DIM + cc0);
            #pragma unroll
            for (int mf = 0; mf < 4; ++mf)
                acc[mf][nf] = __builtin_amdgcn_mfma_f32_16x16x32_bf16(a[mf], bh, acc[mf][nf], 0, 0, 0);
            #pragma unroll
            for (int mf = 0; mf < 4; ++mf)
                acc[mf][nf] = __builtin_amdgcn_mfma_f32_16x16x32_bf16(a[mf], bl, acc[mf][nf], 0, 0, 0);
        }
    }

    // epilogue: per-subgroup (16 codes = 1 n-frag) min across the 16 lanes
    #pragma unroll
    for (int nf = 0; nf < 4; ++nf) {
        const float cck = ccv[code0 + nf * 16 + r16];
        const int sg = (code0 >> 4) + nf;                 // 0..31
        #pragma unroll
        for (int mf = 0; mf < 4; ++mf) {
            #pragma unroll
            for (int r = 0; r < 4; ++r) {
                float s = __builtin_fmaf(-2.0f, acc[mf][nf][r], cck);
                s = fminf(s, __shfl_xor(s, 1));
                s = fminf(s, __shfl_xor(s, 2));
                s = fminf(s, __shfl_xor(s, 4));
                s = fminf(s, __shfl_xor(s, 8));
                if (r16 == 0) {
                    const int pos = (pt << 6) + (mf << 4) + (kg << 2) + r;
                    bd[(size_t)sg * N_POS + pos] = s;
                }
            }
        }
    }
}

// ---------------------------------------------------------------------------
// Exact re-check: 4 workers per pos (codes q*4..+4 of each candidate subgroup).
// Candidate: bd[g] <= min_g bd + EPS (expected ~1.3 subgroups/pos).
// Exact d = fl(fl(zz - 2*chain_dot) + cc) with np-pairwise zz and ascending-c
// FMA chain (identical numerics to R4-R10 passing kernels). Combine across
// workers/subgroups via atomicMin on packed (d_bits<<32 | code): min d, tie ->
// smaller code — exactly np first-min argmin. Deterministic.
// ---------------------------------------------------------------------------
__global__ __launch_bounds__(256) void vq_exact_kernel(
    const float* __restrict__ z, const float* __restrict__ cb,
    const float* __restrict__ ccv, const float* __restrict__ bd,
    u64* __restrict__ key)
{
    const int gid = blockIdx.x * 256 + threadIdx.x;  // 0..262143
    const int pos = gid >> 2;
    const int q   = gid & 3;

    float mt = 3.4e38f;
    for (int g = 0; g < 32; ++g)
        mt = fminf(mt, bd[(size_t)g * N_POS + pos]);

    const float* zr = z + ((size_t)(pos >> 10) << 18) + (pos & 1023);

    // zz: numpy pairwise (proven)
    float s1[8], s2[8];
    #pragma unroll
    for (int j = 0; j < 8; ++j) { s1[j] = 0.f; s2[j] = 0.f; }
    for (int c8 = 0; c8 < 16; ++c8)
        #pragma unroll
        for (int j = 0; j < 8; ++j) {
            float v = zr[(size_t)(c8 * 8 + j) << 10];
            s1[j] = __fadd_rn(s1[j], __fmul_rn(v, v));
        }
    for (int c8 = 16; c8 < 32; ++c8)
        #pragma unroll
        for (int j = 0; j < 8; ++j) {
            float v = zr[(size_t)(c8 * 8 + j) << 10];
            s2[j] = __fadd_rn(s2[j], __fmul_rn(v, v));
        }
    float b1 = __fadd_rn(__fadd_rn(__fadd_rn(s1[0], s1[1]), __fadd_rn(s1[2], s1[3])),
                         __fadd_rn(__fadd_rn(s1[4], s1[5]), __fadd_rn(s1[6], s1[7])));
    float b2 = __fadd_rn(__fadd_rn(__fadd_rn(s2[0], s2[1]), __fadd_rn(s2[2], s2[3])),
                         __fadd_rn(__fadd_rn(s2[4], s2[5]), __fadd_rn(s2[6], s2[7])));
    const float zz = __fadd_rn(b1, b2);

    float bestd = 3.4e38f;
    int   bestc = 0;
    for (int g = 0; g < 32; ++g) {
        if (bd[(size_t)g * N_POS + pos] <= mt + EPS) {
            const int kbase = g * 16 + q * 4;
            #pragma unroll
            for (int kq = 0; kq < 4; ++kq) {
                const int code = kbase + kq;               // ascending order
                const float* crow = cb + (size_t)code * C_DIM;
                float a0 = 0.f;
                for (int c8 = 0; c8 < 32; ++c8) {
                    #pragma unroll
                    for (int j = 0; j < 8; ++j) {
                        const int c = c8 * 8 + j;
                        a0 = __builtin_fmaf(zr[(size_t)c << 10], crow[c], a0);
                    }
                }
                float d = __fadd_rn(__fsub_rn(zz, __fmul_rn(2.0f, a0)), ccv[code]);
                if (d < bestd) { bestd = d; bestc = code; }
            }
        }
    }
    u64 pk = ((u64)__float_as_uint(bestd) << 32) | (unsigned)bestc;
    atomicMin(&key[pos], pk);
}

// ---------------------------------------------------------------------------
// Final: decode key -> idx (ws), out1; per-block d_min sums -> partials[256]
// ---------------------------------------------------------------------------
__global__ __launch_bounds__(256) void vq_final_kernel(
    const u64* __restrict__ key, int* __restrict__ idx,
    float* __restrict__ out1, float* __restrict__ partials)
{
    const int t = threadIdx.x;
    const int pos = blockIdx.x * 256 + t;
    u64 k = key[pos];
    const int code = (int)(unsigned)(k & 0xffffffffull);
    const float d  = __uint_as_float((unsigned)(k >> 32));
    idx[pos]  = code;
    out1[pos] = (float)code;

    __shared__ float s[256];
    s[t] = d;
    __syncthreads();
    for (int off = 128; off > 0; off >>= 1) {
        if (t < off) s[t] += s[t + off];
        __syncthreads();
    }
    if (t == 0) partials[blockIdx.x] = s[0];
}

// ---------------------------------------------------------------------------
// Gather: out0[b, c, hw] = cb[code][c]  (f32) — proven kernel
// ---------------------------------------------------------------------------
__global__ __launch_bounds__(256) void vq_gather_kernel(
    const float* __restrict__ cb, const int* __restrict__ idx,
    float* __restrict__ out0)
{
    const int blk = blockIdx.x;          // 1024
    const int b   = blk >> 4;
    const int hw0 = (blk & 15) << 6;
    const int lane = threadIdx.x & 63;
    const int w    = threadIdx.x >> 6;

    __shared__ int sidx[64];
    if (threadIdx.x < 64) sidx[threadIdx.x] = idx[(blk << 6) + threadIdx.x];
    __syncthreads();

    const int code = sidx[lane];
    const float4* crow4 = reinterpret_cast<const float4*>(cb + ((size_t)code << 8) + (w << 6));
    float* ob = out0 + ((size_t)b << 18) + ((size_t)(w * 64) << 10) + hw0 + lane;
    #pragma unroll 4
    for (int j4 = 0; j4 < 16; ++j4) {
        float4 v = crow4[j4];
        ob[(size_t)(j4 * 4 + 0) << 10] = v.x;
        ob[(size_t)(j4 * 4 + 1) << 10] = v.y;
        ob[(size_t)(j4 * 4 + 2) << 10] = v.z;
        ob[(size_t)(j4 * 4 + 3) << 10] = v.w;
    }
}

// ---------------------------------------------------------------------------
// Finalize: loss = 1.25 * sum(partials[0..255]) / 2^24
// ---------------------------------------------------------------------------
__global__ __launch_bounds__(256) void vq_finalize_kernel(
    const float* __restrict__ partials, float* __restrict__ out2)
{
    __shared__ float s[256];
    const int t = threadIdx.x;
    s[t] = partials[t];
    __syncthreads();
    for (int off = 128; off > 0; off >>= 1) {
        if (t < off) s[t] += s[t + off];
        __syncthreads();
    }
    if (t == 0)
        out2[0] = 1.25f * (s[0] * (1.0f / 16777216.0f));
}

// ---------------------------------------------------------------------------
extern "C" void kernel_launch(void* const* d_in, const int* in_sizes, int n_in,
                              void* d_out, int out_size, void* d_ws, size_t ws_size,
                              hipStream_t stream)
{
    const float* z  = (const float*)d_in[0];
    const float* cb = (const float*)d_in[1];

    float* out0 = (float*)d_out;
    float* out1 = out0 + OUT0_ELEMS;
    float* out2 = out1 + OUT1_ELEMS;

    // scratch carved from out0 (all dead before gather overwrites):
    __hip_bfloat16* Zh = (__hip_bfloat16*)out0;     // [0, 8388608) fl = 32MB
    float* bd  = out0 + 8388608;                    // 32*65536 f32 = [8388608, 10485760)
    u64*   key = (u64*)(out0 + 10485760);           // 65536 u64 = 512KB

    // ws (~772 KB):
    float* wsf      = (float*)d_ws;
    float* ccv      = wsf;                                   // 512 f32
    float* partials = wsf + 512;                             // 256 f32
    __hip_bfloat16* Ch = (__hip_bfloat16*)(wsf + 1024);      // 131072 bf16
    __hip_bfloat16* Cl = (__hip_bfloat16*)(wsf + 66560);     // 131072 bf16
    int* idx        = (int*)(wsf + 132096);                  // 65536 i32

    hipMemsetAsync(key, 0xFF, N_POS * sizeof(u64), stream);
    hipLaunchKernelGGL(vq_convcb_kernel,  dim3(512),  dim3(256), 0, stream, cb, Ch, Cl);
    hipLaunchKernelGGL(vq_cc_kernel,      dim3(2),    dim3(256), 0, stream, cb, ccv);
    hipLaunchKernelGGL(vq_splitz_kernel,  dim3(2048), dim3(256), 0, stream, z, Zh);
    hipLaunchKernelGGL(vq_mfma_kernel,    dim3(2048), dim3(256), 0, stream,
                       Zh, Ch, Cl, ccv, bd);
    hipLaunchKernelGGL(vq_exact_kernel,   dim3(1024), dim3(256), 0, stream,
                       z, cb, ccv, bd, key);
    hipLaunchKernelGGL(vq_final_kernel,   dim3(256),  dim3(256), 0, stream,
                       key, idx, out1, partials);
    hipLaunchKernelGGL(vq_gather_kernel,  dim3(1024), dim3(256), 0, stream, cb, idx, out0);
    hipLaunchKernelGGL(vq_finalize_kernel, dim3(1),   dim3(256), 0, stream, partials, out2);
}

// Round 12
// 401.751 us; speedup vs baseline: 3.3341x; 3.3341x over previous
//
#include <hip/hip_runtime.h>
#include <hip/hip_bf16.h>

typedef __attribute__((ext_vector_type(8))) short short8;
typedef __attribute__((ext_vector_type(4))) float f32x4;
typedef unsigned long long u64;

// z: [64, 256, 32, 32] f32 ; codebook: [512, 256] f32
// d_out f32: [z_q_st (16777216) | indices (65536) | loss (1)]
#define C_DIM   256
#define K_CODES 512
#define N_POS   65536
#define OUT0_ELEMS 16777216
#define OUT1_ELEMS 65536
#define EPS 0.06f   // >= 2*approx-error bound (~0.042 worst-case)
#define LCAP 2048   // candidate list cap per 32-pos block

// ---------------------------------------------------------------------------
// codebook -> bf16 hi/lo rows
// ---------------------------------------------------------------------------
__global__ __launch_bounds__(256) void vq_convcb_kernel(const float* __restrict__ cb,
    __hip_bfloat16* __restrict__ Ch, __hip_bfloat16* __restrict__ Cl)
{
    const int i = blockIdx.x * 256 + threadIdx.x;
    float v = cb[i];
    __hip_bfloat16 h = __float2bfloat16(v);
    __hip_bfloat16 l = __float2bfloat16(v - __bfloat162float(h));
    Ch[i] = h; Cl[i] = l;
}

// ---------------------------------------------------------------------------
// cc[k] = sum_c cb[k][c]^2, numpy pairwise order (proven)
// ---------------------------------------------------------------------------
__global__ __launch_bounds__(256) void vq_cc_kernel(const float* __restrict__ cb,
                                                    float* __restrict__ cc)
{
    const int k = blockIdx.x * 256 + threadIdx.x;
    const float* row = cb + (size_t)k * C_DIM;
    float s1[8], s2[8];
    #pragma unroll
    for (int j = 0; j < 8; ++j) { s1[j] = 0.f; s2[j] = 0.f; }
    for (int c8 = 0; c8 < 16; ++c8)
        #pragma unroll
        for (int j = 0; j < 8; ++j) {
            float v = row[c8 * 8 + j];
            s1[j] = __fadd_rn(s1[j], __fmul_rn(v, v));
        }
    for (int c8 = 16; c8 < 32; ++c8)
        #pragma unroll
        for (int j = 0; j < 8; ++j) {
            float v = row[c8 * 8 + j];
            s2[j] = __fadd_rn(s2[j], __fmul_rn(v, v));
        }
    float b1 = __fadd_rn(__fadd_rn(__fadd_rn(s1[0], s1[1]), __fadd_rn(s1[2], s1[3])),
                         __fadd_rn(__fadd_rn(s1[4], s1[5]), __fadd_rn(s1[6], s1[7])));
    float b2 = __fadd_rn(__fadd_rn(__fadd_rn(s2[0], s2[1]), __fadd_rn(s2[2], s2[3])),
                         __fadd_rn(__fadd_rn(s2[4], s2[5]), __fadd_rn(s2[6], s2[7])));
    cc[k] = __fadd_rn(b1, b2);
}

// ---------------------------------------------------------------------------
// zz[pos] = sum_c z[pos][c]^2, np-pairwise (proven R5-R10 kernel)
// ---------------------------------------------------------------------------
__global__ __launch_bounds__(256) void vq_zz_kernel(const float* __restrict__ z,
                                                    float* __restrict__ zz)
{
    const int pos = blockIdx.x * 256 + threadIdx.x;
    const float* zp = z + ((size_t)(pos >> 10) << 18) + (pos & 1023);
    float s1[8], s2[8];
    #pragma unroll
    for (int j = 0; j < 8; ++j) { s1[j] = 0.f; s2[j] = 0.f; }
    for (int c8 = 0; c8 < 16; ++c8)
        #pragma unroll
        for (int j = 0; j < 8; ++j) {
            float v = zp[(size_t)(c8 * 8 + j) << 10];
            s1[j] = __fadd_rn(s1[j], __fmul_rn(v, v));
        }
    for (int c8 = 16; c8 < 32; ++c8)
        #pragma unroll
        for (int j = 0; j < 8; ++j) {
            float v = zp[(size_t)(c8 * 8 + j) << 10];
            s2[j] = __fadd_rn(s2[j], __fmul_rn(v, v));
        }
    float b1 = __fadd_rn(__fadd_rn(__fadd_rn(s1[0], s1[1]), __fadd_rn(s1[2], s1[3])),
                         __fadd_rn(__fadd_rn(s1[4], s1[5]), __fadd_rn(s1[6], s1[7])));
    float b2 = __fadd_rn(__fadd_rn(__fadd_rn(s2[0], s2[1]), __fadd_rn(s2[2], s2[3])),
                         __fadd_rn(__fadd_rn(s2[4], s2[5]), __fadd_rn(s2[6], s2[7])));
    zz[pos] = __fadd_rn(b1, b2);
}

// ---------------------------------------------------------------------------
// z -> Zh bf16 in [pos][c] layout (unchanged, passed)
// ---------------------------------------------------------------------------
__global__ __launch_bounds__(256) void vq_splitz_kernel(const float* __restrict__ z,
    __hip_bfloat16* __restrict__ Zh)
{
    const int tid = threadIdx.x;
    const int p   = blockIdx.x * 32 + (tid >> 3);
    const int c8  = tid & 7;
    const float* zb = z + ((size_t)(p >> 10) << 18) + (p & 1023);
    __hip_bfloat16* out = Zh + (size_t)p * C_DIM;
    #pragma unroll
    for (int q = 0; q < 4; ++q) {
        const int c0 = q * 64 + c8 * 8;
        short8 pk;
        #pragma unroll
        for (int j = 0; j < 8; ++j) {
            float v = zb[(size_t)(c0 + j) << 10];
            __hip_bfloat16 h = __float2bfloat16(v);
            pk[j] = *reinterpret_cast<short*>(&h);
        }
        *reinterpret_cast<short8*>(out + c0) = pk;
    }
}

// ---------------------------------------------------------------------------
// MFMA screen (unchanged, passed): bd[sg][pos] = min over 16 codes of
// cc - 2*(Zh.Ch + Zh.Cl)
// ---------------------------------------------------------------------------
__global__ __launch_bounds__(256) void vq_mfma_kernel(
    const __hip_bfloat16* __restrict__ Zh, const __hip_bfloat16* __restrict__ Ch,
    const __hip_bfloat16* __restrict__ Cl, const float* __restrict__ ccv,
    float* __restrict__ bd)
{
    const int blk  = blockIdx.x;
    const int cg   = blk & 1;
    const int pt   = blk >> 1;
    const int tid  = threadIdx.x;
    const int lane = tid & 63;
    const int w    = tid >> 6;
    const int r16  = lane & 15;
    const int kg   = lane >> 4;
    const int code0 = cg * 256 + w * 64;

    f32x4 acc[4][4];
    #pragma unroll
    for (int mf = 0; mf < 4; ++mf)
        #pragma unroll
        for (int nf = 0; nf < 4; ++nf) acc[mf][nf] = (f32x4){0.f, 0.f, 0.f, 0.f};

    for (int kk = 0; kk < 8; ++kk) {
        const int cc0 = kk * 32 + kg * 8;
        short8 a[4];
        #pragma unroll
        for (int mf = 0; mf < 4; ++mf) {
            const int pos = (pt << 6) + (mf << 4) + r16;
            a[mf] = *reinterpret_cast<const short8*>(Zh + (size_t)pos * C_DIM + cc0);
        }
        #pragma unroll
        for (int nf = 0; nf < 4; ++nf) {
            const int code = code0 + nf * 16 + r16;
            short8 bh = *reinterpret_cast<const short8*>(Ch + (size_t)code * C_DIM + cc0);
            short8 bl = *reinterpret_cast<const short8*>(Cl + (size_t)code * C_DIM + cc0);
            #pragma unroll
            for (int mf = 0; mf < 4; ++mf)
                acc[mf][nf] = __builtin_amdgcn_mfma_f32_16x16x32_bf16(a[mf], bh, acc[mf][nf], 0, 0, 0);
            #pragma unroll
            for (int mf = 0; mf < 4; ++mf)
                acc[mf][nf] = __builtin_amdgcn_mfma_f32_16x16x32_bf16(a[mf], bl, acc[mf][nf], 0, 0, 0);
        }
    }

    #pragma unroll
    for (int nf = 0; nf < 4; ++nf) {
        const float cck = ccv[code0 + nf * 16 + r16];
        const int sg = (code0 >> 4) + nf;
        #pragma unroll
        for (int mf = 0; mf < 4; ++mf) {
            #pragma unroll
            for (int r = 0; r < 4; ++r) {
                float s = __builtin_fmaf(-2.0f, acc[mf][nf][r], cck);
                s = fminf(s, __shfl_xor(s, 1));
                s = fminf(s, __shfl_xor(s, 2));
                s = fminf(s, __shfl_xor(s, 4));
                s = fminf(s, __shfl_xor(s, 8));
                if (r16 == 0) {
                    const int pos = (pt << 6) + (mf << 4) + (kg << 2) + r;
                    bd[(size_t)sg * N_POS + pos] = s;
                }
            }
        }
    }
}

// ---------------------------------------------------------------------------
// Exact re-check v2: block = 32 positions. z staged in LDS (read HBM once,
// coalesced). Candidates compacted into an LDS list (per-code entries);
// 256 threads drain the list. Chain numerics identical to R11 (passed):
// ascending-c single-acc FMA, d = fl(fl(zz-2*dot)+cc); atomicMin on packed
// (d_bits<<32|code) = np first-min argmin. Overflow (cnt>LCAP): pusher
// processes those codes inline — correctness preserved.
// ---------------------------------------------------------------------------
__global__ __launch_bounds__(256) void vq_exact_kernel(
    const float* __restrict__ z, const float* __restrict__ cb,
    const float* __restrict__ ccv, const float* __restrict__ zzbuf,
    const float* __restrict__ bd, u64* __restrict__ key)
{
    const int blk  = blockIdx.x;        // 0..2047, 32 pos each
    const int pos0 = blk << 5;
    const int tid  = threadIdx.x;

    __shared__ float zl[C_DIM * 32];    // 32 KB, zl[c*32 + p]
    __shared__ float mt_s[32];
    __shared__ unsigned short list[LCAP];
    __shared__ int cnt;

    // ---- stage z: 32 iterations, fully coalesced (32 consecutive pos per c)
    const float* zg = z + ((size_t)(pos0 >> 10) << 18) + (pos0 & 1023);
    for (int i = 0; i < 32; ++i) {
        const int idx = i * 256 + tid;          // 8192 elements
        const int c = idx >> 5;
        const int p = idx & 31;
        zl[c * 32 + p] = zg[((size_t)c << 10) + p];
    }
    if (tid == 0) cnt = 0;
    // ---- per-pos screen min
    if (tid < 32) {
        float m = 3.4e38f;
        for (int g = 0; g < 32; ++g)
            m = fminf(m, bd[(size_t)g * N_POS + pos0 + tid]);
        mt_s[tid] = m;
    }
    __syncthreads();

    // ---- candidate scan & compaction: 8 workers x 32 pos
    {
        const int p = tid & 31;
        const int q = tid >> 5;                 // 0..7, 4 subgroups each
        const float thr = mt_s[p] + EPS;
        const float zzv = zzbuf[pos0 + p];
        for (int g = q * 4; g < q * 4 + 4; ++g) {
            if (bd[(size_t)g * N_POS + pos0 + p] <= thr) {
                int base = atomicAdd(&cnt, 16);
                if (base + 16 <= LCAP) {
                    #pragma unroll
                    for (int j = 0; j < 16; ++j)
                        list[base + j] = (unsigned short)((p << 9) | (g * 16 + j));
                } else {
                    // overflow: process these 16 codes inline (rare/never)
                    float bestd = 3.4e38f; int bestc = 0;
                    for (int j = 0; j < 16; ++j) {
                        const int code = g * 16 + j;
                        const float4* crow4 = reinterpret_cast<const float4*>(cb + ((size_t)code << 8));
                        float a0 = 0.f;
                        for (int c4 = 0; c4 < 64; ++c4) {
                            float4 cv = crow4[c4];
                            a0 = __builtin_fmaf(zl[(c4 * 4 + 0) * 32 + p], cv.x, a0);
                            a0 = __builtin_fmaf(zl[(c4 * 4 + 1) * 32 + p], cv.y, a0);
                            a0 = __builtin_fmaf(zl[(c4 * 4 + 2) * 32 + p], cv.z, a0);
                            a0 = __builtin_fmaf(zl[(c4 * 4 + 3) * 32 + p], cv.w, a0);
                        }
                        float d = __fadd_rn(__fsub_rn(zzv, __fmul_rn(2.0f, a0)), ccv[code]);
                        if (d < bestd) { bestd = d; bestc = code; }
                    }
                    u64 pk = ((u64)__float_as_uint(bestd) << 32) | (unsigned)bestc;
                    atomicMin(&key[pos0 + p], pk);
                }
            }
        }
    }
    __syncthreads();

    // ---- drain list: one code-chain per entry
    const int total = min(cnt, LCAP);
    for (int e = tid; e < total; e += 256) {
        const unsigned short ent = list[e];
        const int p    = ent >> 9;
        const int code = ent & 511;
        const float4* crow4 = reinterpret_cast<const float4*>(cb + ((size_t)code << 8));
        float a0 = 0.f;
        for (int c4 = 0; c4 < 64; ++c4) {
            float4 cv = crow4[c4];
            a0 = __builtin_fmaf(zl[(c4 * 4 + 0) * 32 + p], cv.x, a0);
            a0 = __builtin_fmaf(zl[(c4 * 4 + 1) * 32 + p], cv.y, a0);
            a0 = __builtin_fmaf(zl[(c4 * 4 + 2) * 32 + p], cv.z, a0);
            a0 = __builtin_fmaf(zl[(c4 * 4 + 3) * 32 + p], cv.w, a0);
        }
        float d = __fadd_rn(__fsub_rn(zzbuf[pos0 + p], __fmul_rn(2.0f, a0)), ccv[code]);
        u64 pk = ((u64)__float_as_uint(d) << 32) | (unsigned)code;
        atomicMin(&key[pos0 + p], pk);
    }
}

// ---------------------------------------------------------------------------
// Final: decode key -> idx, out1; per-block d_min sums -> partials[256]
// ---------------------------------------------------------------------------
__global__ __launch_bounds__(256) void vq_final_kernel(
    const u64* __restrict__ key, int* __restrict__ idx,
    float* __restrict__ out1, float* __restrict__ partials)
{
    const int t = threadIdx.x;
    const int pos = blockIdx.x * 256 + t;
    u64 k = key[pos];
    const int code = (int)(unsigned)(k & 0xffffffffull);
    const float d  = __uint_as_float((unsigned)(k >> 32));
    idx[pos]  = code;
    out1[pos] = (float)code;

    __shared__ float s[256];
    s[t] = d;
    __syncthreads();
    for (int off = 128; off > 0; off >>= 1) {
        if (t < off) s[t] += s[t + off];
        __syncthreads();
    }
    if (t == 0) partials[blockIdx.x] = s[0];
}

// ---------------------------------------------------------------------------
// Gather: out0[b, c, hw] = cb[code][c]  (f32) — proven kernel
// ---------------------------------------------------------------------------
__global__ __launch_bounds__(256) void vq_gather_kernel(
    const float* __restrict__ cb, const int* __restrict__ idx,
    float* __restrict__ out0)
{
    const int blk = blockIdx.x;          // 1024
    const int b   = blk >> 4;
    const int hw0 = (blk & 15) << 6;
    const int lane = threadIdx.x & 63;
    const int w    = threadIdx.x >> 6;

    __shared__ int sidx[64];
    if (threadIdx.x < 64) sidx[threadIdx.x] = idx[(blk << 6) + threadIdx.x];
    __syncthreads();

    const int code = sidx[lane];
    const float4* crow4 = reinterpret_cast<const float4*>(cb + ((size_t)code << 8) + (w << 6));
    float* ob = out0 + ((size_t)b << 18) + ((size_t)(w * 64) << 10) + hw0 + lane;
    #pragma unroll 4
    for (int j4 = 0; j4 < 16; ++j4) {
        float4 v = crow4[j4];
        ob[(size_t)(j4 * 4 + 0) << 10] = v.x;
        ob[(size_t)(j4 * 4 + 1) << 10] = v.y;
        ob[(size_t)(j4 * 4 + 2) << 10] = v.z;
        ob[(size_t)(j4 * 4 + 3) << 10] = v.w;
    }
}

// ---------------------------------------------------------------------------
// Finalize: loss = 1.25 * sum(partials[0..255]) / 2^24
// ---------------------------------------------------------------------------
__global__ __launch_bounds__(256) void vq_finalize_kernel(
    const float* __restrict__ partials, float* __restrict__ out2)
{
    __shared__ float s[256];
    const int t = threadIdx.x;
    s[t] = partials[t];
    __syncthreads();
    for (int off = 128; off > 0; off >>= 1) {
        if (t < off) s[t] += s[t + off];
        __syncthreads();
    }
    if (t == 0)
        out2[0] = 1.25f * (s[0] * (1.0f / 16777216.0f));
}

// ---------------------------------------------------------------------------
extern "C" void kernel_launch(void* const* d_in, const int* in_sizes, int n_in,
                              void* d_out, int out_size, void* d_ws, size_t ws_size,
                              hipStream_t stream)
{
    const float* z  = (const float*)d_in[0];
    const float* cb = (const float*)d_in[1];

    float* out0 = (float*)d_out;
    float* out1 = out0 + OUT0_ELEMS;
    float* out2 = out1 + OUT1_ELEMS;

    // scratch carved from out0 (all dead before gather overwrites):
    __hip_bfloat16* Zh = (__hip_bfloat16*)out0;     // 16M bf16 = [0, 8388608) f32-slots
    float* bd  = out0 + 8388608;                    // 32*65536 f32 = [8388608, 10485760)
    u64*   key = (u64*)(out0 + 10485760);           // 65536 u64   = [10485760, 10616832)
    float* zzb = out0 + 10616832;                   // 65536 f32   = [10616832, 10682368)

    // ws (~772 KB):
    float* wsf      = (float*)d_ws;
    float* ccv      = wsf;                                   // 512 f32
    float* partials = wsf + 512;                             // 256 f32
    __hip_bfloat16* Ch = (__hip_bfloat16*)(wsf + 1024);      // 131072 bf16
    __hip_bfloat16* Cl = (__hip_bfloat16*)(wsf + 66560);     // 131072 bf16
    int* idx        = (int*)(wsf + 132096);                  // 65536 i32

    hipMemsetAsync(key, 0xFF, N_POS * sizeof(u64), stream);
    hipLaunchKernelGGL(vq_convcb_kernel,  dim3(512),  dim3(256), 0, stream, cb, Ch, Cl);
    hipLaunchKernelGGL(vq_cc_kernel,      dim3(2),    dim3(256), 0, stream, cb, ccv);
    hipLaunchKernelGGL(vq_splitz_kernel,  dim3(2048), dim3(256), 0, stream, z, Zh);
    hipLaunchKernelGGL(vq_zz_kernel,      dim3(256),  dim3(256), 0, stream, z, zzb);
    hipLaunchKernelGGL(vq_mfma_kernel,    dim3(2048), dim3(256), 0, stream,
                       Zh, Ch, Cl, ccv, bd);
    hipLaunchKernelGGL(vq_exact_kernel,   dim3(2048), dim3(256), 0, stream,
                       z, cb, ccv, zzb, bd, key);
    hipLaunchKernelGGL(vq_final_kernel,   dim3(256),  dim3(256), 0, stream,
                       key, idx, out1, partials);
    hipLaunchKernelGGL(vq_gather_kernel,  dim3(1024), dim3(256), 0, stream, cb, idx, out0);
    hipLaunchKernelGGL(vq_finalize_kernel, dim3(1),   dim3(256), 0, stream, partials, out2);
}